// Round 11
// baseline (335.489 us; speedup 1.0000x reference)
//
#include <hip/hip_runtime.h>

#define BATCH 4
#define NHEADS 3
#define SEQ 2048
#define HDIM 256
#define EMBD 768
#define MTOT (BATCH*SEQ)          // 8192
#define WSZ (NHEADS*EMBD*HDIM)    // 589824 per projection weight

typedef unsigned short u16x8 __attribute__((ext_vector_type(8)));
typedef unsigned short u16x4 __attribute__((ext_vector_type(4)));
typedef __bf16 bf16x8 __attribute__((ext_vector_type(8)));
typedef float fx4 __attribute__((ext_vector_type(4)));

__device__ __forceinline__ unsigned short f2bf(float x) {
    union { float f; unsigned int u; } v; v.f = x;
    unsigned int r = v.u + 0x7fffu + ((v.u >> 16) & 1u);
    return (unsigned short)(r >> 16);
}

__device__ __forceinline__ fx4 mfma16(u16x8 a, u16x8 b, fx4 c) {
    return __builtin_amdgcn_mfma_f32_16x16x32_bf16(
        __builtin_bit_cast(bf16x8, a), __builtin_bit_cast(bf16x8, b), c, 0, 0, 0);
}

// async global->LDS, 16B per lane. LDS dest must be wave-uniform-base +
// lane*16 contiguous (m97/m104 constraint) — callers pass &lds[t*8shorts].
__device__ __forceinline__ void gl_lds16(const unsigned short* g, unsigned short* l) {
    __builtin_amdgcn_global_load_lds(
        (const __attribute__((address_space(1))) unsigned int*)g,
        (__attribute__((address_space(3))) unsigned int*)l, 16, 0, 0);
}

// attn work schedule per (b,h): entries qt*4+kc, kc in {0,1}=k-chunk (qt>=16,
// writes partials), kc=3 = whole causal range (qt<16, writes heads directly).
// (exact R5 schedule — 48 entries x 12 bh = 576 blocks; this round the 576
// blocks are issued as TWO 288-block launches taking even/odd entries, purely
// for profile decomposition — kernel body identical to the R5 winner.)
__device__ const unsigned char attn_sched[48] = {
    124,125, 63, 120,121, 116,117, 59, 112,113, 108,109, 55, 104,105,
    100,101, 51,  96, 97,  92, 93, 47,  88, 89,  84, 85, 43,  80, 81,
     76, 77, 39,  72, 73,  68, 69, 35,  64, 65,  31, 27, 23, 19, 15,
     11,  7,  3
};

// ---------------------------------------------------------------------------
// Kernel 1: cast A inputs fp32->bf16 + weight cast/transpose. (unchanged)
// ---------------------------------------------------------------------------
__global__ __launch_bounds__(256) void castAw_kernel(
    const float* __restrict__ Ak, const float* __restrict__ Av,
    const float* __restrict__ Aq,
    const float* __restrict__ Wk, const float* __restrict__ Wv,
    const float* __restrict__ Wq, const float* __restrict__ Wo,
    unsigned short* __restrict__ Abf, unsigned short* __restrict__ Wt,
    unsigned short* __restrict__ Wot)
{
    __shared__ float tile[64][65];
    int bx = blockIdx.x;
    if (bx < 9216) {            // A cast: 3 * 8192*768 elems, 8 per thread
        int e = (bx * 256 + threadIdx.x) * 8;
        int t = e / (MTOT * EMBD);
        int r = e - t * (MTOT * EMBD);
        const float* A = (t == 0) ? Ak : (t == 1) ? Av : Aq;
        const fx4* s = (const fx4*)(A + r);
        fx4 v0 = s[0], v1 = s[1];
        u16x8 o;
        o[0]=f2bf(v0[0]); o[1]=f2bf(v0[1]); o[2]=f2bf(v0[2]); o[3]=f2bf(v0[3]);
        o[4]=f2bf(v1[0]); o[5]=f2bf(v1[1]); o[6]=f2bf(v1[2]); o[7]=f2bf(v1[3]);
        *(u16x8*)(Abf + e) = o;
        return;
    }
    int z = bx - 9216;          // weight transpose via 64x64 LDS tile
    const float* src; unsigned short* dst;
    int src_ld, dst_ld, e0, f0;
    if (z < 432) {
        int t = z / 144, rem = z - t * 144;
        int h = rem / 48, tl = rem - h * 48;
        e0 = (tl % 12) * 64; f0 = (tl / 12) * 64;
        const float* W = (t == 0) ? Wk : (t == 1) ? Wv : Wq;
        src = W + h * 768 * 256; src_ld = 256;
        dst = Wt + t * WSZ + h * 256 * 768; dst_ld = 768;
    } else {
        int zz = z - 432;
        e0 = (zz % 12) * 64; f0 = (zz / 12) * 64;
        src = Wo; src_ld = 768;
        dst = Wot; dst_ld = 768;
    }
    int tx = threadIdx.x & 63, ty4 = threadIdx.x >> 6;
    #pragma unroll
    for (int i = 0; i < 16; ++i) {
        int r = ty4 + i * 4;
        tile[r][tx] = src[(e0 + r) * src_ld + f0 + tx];
    }
    __syncthreads();
    #pragma unroll
    for (int i = 0; i < 16; ++i) {
        int r = ty4 + i * 4;
        dst[(f0 + r) * dst_ld + e0 + tx] = f2bf(tile[tx][r]);
    }
}

// ---------------------------------------------------------------------------
// Kernel 2: projection GEMM, BK=64 + XOR chunk swizzle (exact R5 winner).
// ---------------------------------------------------------------------------
__global__ __launch_bounds__(256) void proj_kernel(
    const unsigned short* __restrict__ Abf, const unsigned short* __restrict__ Wt,
    unsigned short* __restrict__ Kg, unsigned short* __restrict__ Vg,
    unsigned short* __restrict__ Qg)
{
    __shared__ alignas(16) unsigned short S[17408];
    unsigned short* As = S;
    unsigned short* Bs = S + 8192;

    int z = blockIdx.z;
    const unsigned short* A = Abf + z * (MTOT * EMBD);
    int m0 = blockIdx.x * 128;
    int h = blockIdx.y >> 1, fbase = (blockIdx.y & 1) * 128;
    const unsigned short* W = Wt + z * WSZ + (h * 256 + fbase) * EMBD;

    int tid = threadIdx.x;
    int w = tid >> 6, ln = tid & 63;
    int lane16 = ln & 15, quad = ln >> 4;
    int mw = (w & 1) * 64, nw = (w >> 1) * 64;

    fx4 acc[4][4];
    #pragma unroll
    for (int i = 0; i < 4; ++i)
        #pragma unroll
        for (int j = 0; j < 4; ++j) acc[i][j] = (fx4){0.f, 0.f, 0.f, 0.f};

    const unsigned short *Ag[4], *Wg[4];
    #pragma unroll
    for (int i = 0; i < 4; ++i) {
        int c = tid + 256 * i;
        int R = c >> 3;
        int So = (((c & 7) ^ (R & 7)) * 8);
        Ag[i] = A + (m0 + R) * EMBD + So;
        Wg[i] = W + R * EMBD + So;
    }

    int ca0 = ((quad + 0) ^ (lane16 & 7)) * 8;
    int ca1 = ((quad + 4) ^ (lane16 & 7)) * 8;

    for (int kb = 0; kb < EMBD; kb += 64) {
        __syncthreads();
        #pragma unroll
        for (int i = 0; i < 4; ++i) {
            gl_lds16(Ag[i] + kb, &As[(tid + 256 * i) * 8]);
            gl_lds16(Wg[i] + kb, &Bs[(tid + 256 * i) * 8]);
        }
        __syncthreads();

        #pragma unroll
        for (int kh = 0; kh < 2; ++kh) {
            int co = kh ? ca1 : ca0;
            u16x8 af[4], bf[4];
            #pragma unroll
            for (int i = 0; i < 4; ++i) {
                af[i] = *(const u16x8*)&As[(mw + i * 16 + lane16) * 64 + co];
                bf[i] = *(const u16x8*)&Bs[(nw + i * 16 + lane16) * 64 + co];
            }
            #pragma unroll
            for (int i = 0; i < 4; ++i)
                #pragma unroll
                for (int j = 0; j < 4; ++j)
                    acc[i][j] = mfma16(af[i], bf[j], acc[i][j]);
        }
    }

    __syncthreads();
    int b = m0 >> 11, sq0 = m0 & 2047;

    if (z == 1) {
        #pragma unroll
        for (int i = 0; i < 4; ++i)
            #pragma unroll
            for (int j = 0; j < 4; ++j) {
                int fl = nw + j * 16 + lane16;
                int ml = mw + i * 16 + quad * 4;
                u16x4 pk;
                pk[0] = f2bf(acc[i][j][0]); pk[1] = f2bf(acc[i][j][1]);
                pk[2] = f2bf(acc[i][j][2]); pk[3] = f2bf(acc[i][j][3]);
                *(u16x4*)&S[fl * 136 + ml] = pk;
            }
        __syncthreads();
        int fl = tid >> 1, mseg = (tid & 1) * 64;
        const unsigned short* srcp = &S[fl * 136 + mseg];
        unsigned short* dstp = Vg + ((b * NHEADS + h) * HDIM + fbase + fl) * SEQ + sq0 + mseg;
        #pragma unroll
        for (int c = 0; c < 8; ++c)
            *(u16x8*)(dstp + c * 8) = *(const u16x8*)(srcp + c * 8);
    } else {
        #pragma unroll
        for (int i = 0; i < 4; ++i)
            #pragma unroll
            for (int j = 0; j < 4; ++j) {
                int fl = nw + j * 16 + lane16;
                int ml = mw + i * 16 + quad * 4;
                #pragma unroll
                for (int r = 0; r < 4; ++r)
                    S[(ml + r) * 136 + fl] = f2bf(acc[i][j][r]);
            }
        __syncthreads();
        unsigned short* dst0 = (z == 0) ? Kg : Qg;
        int ml = tid >> 1, fseg = (tid & 1) * 64;
        const unsigned short* srcp = &S[ml * 136 + fseg];
        unsigned short* dstp = dst0 + ((b * NHEADS + h) * SEQ + sq0 + ml) * HDIM + fbase + fseg;
        #pragma unroll
        for (int c = 0; c < 8; ++c)
            *(u16x8*)(dstp + c * 8) = *(const u16x8*)(srcp + c * 8);
    }
}

// ---------------------------------------------------------------------------
// Kernel 3: causal attention — EXACT R5 winner body (80us). CHANGED this
// round only in scheduling: issued as TWO 288-block launches (phase 0/1 take
// even/odd schedule entries — balanced halves) so the per-dispatch profile
// threshold drops to ~45us and non-attn kernels become visible in top-5.
// ---------------------------------------------------------------------------
__global__ __launch_bounds__(256) void attn_kernel(
    const unsigned short* __restrict__ Kg, const unsigned short* __restrict__ Vg,
    const unsigned short* __restrict__ Qg, unsigned short* __restrict__ heads,
    float* __restrict__ Opart, float* __restrict__ Lpart, int phase)
{
    __shared__ alignas(16) unsigned short Ks[32 * 264];
    __shared__ alignas(16) unsigned short Vs[256 * 40];

    int bh = blockIdx.x % 12;
    int ent = attn_sched[(blockIdx.x / 12) * 2 + phase];
    int qt = ent >> 2, kc = ent & 3;
    int tid = threadIdx.x;
    int w = tid >> 6, ln = tid & 63;
    int lane16 = ln & 15, quad = ln >> 4;
    int q0w = qt * 64 + w * 16;

    const unsigned short* Kbase = Kg + bh * (SEQ * HDIM);
    const unsigned short* Vbase = Vg + bh * (SEQ * HDIM);  // [f][s]
    const unsigned short* Qbase = Qg + bh * (SEQ * HDIM);

    u16x8 qf[8];
    {
        const unsigned short* qrow = Qbase + (q0w + lane16) * HDIM + quad * 8;
        #pragma unroll
        for (int c = 0; c < 8; ++c) qf[c] = *(const u16x8*)(qrow + c * 32);
    }

    fx4 o[16];
    #pragma unroll
    for (int i = 0; i < 16; ++i) o[i] = (fx4){0.f, 0.f, 0.f, 0.f};
    float lsum = 0.f;

    const float Cs2 = 0.03188010519640429f;  // log2(e)/sqrt(2048)

    int t0, t1;
    if (kc == 3) { t0 = 0; t1 = 2 * qt + 2; }
    else         { t0 = kc * (qt + 1); t1 = t0 + qt + 1; }

    int ksrow = tid >> 3, kseg = tid & 7;
    const unsigned short* kstage = Kbase + ksrow * HDIM + kseg * 32;
    const unsigned short* vstage = Vbase + tid * SEQ;

    u16x8 kreg[4], vreg[4];
    {
        int k0 = t0 * 32;
        #pragma unroll
        for (int j = 0; j < 4; ++j) {
            kreg[j] = *(const u16x8*)(kstage + k0 * HDIM + j * 8);
            vreg[j] = *(const u16x8*)(vstage + k0 + j * 8);
        }
    }

    for (int kt = t0; kt < t1; ++kt) {
        __syncthreads();
        {
            u16x8* kd = (u16x8*)&Ks[ksrow * 264 + kseg * 32];
            kd[0] = kreg[0]; kd[1] = kreg[1]; kd[2] = kreg[2]; kd[3] = kreg[3];
            u16x8* vd = (u16x8*)&Vs[tid * 40];
            vd[0] = vreg[0]; vd[1] = vreg[1]; vd[2] = vreg[2]; vd[3] = vreg[3];
        }
        if (kt + 1 < t1) {
            int k0n = (kt + 1) * 32;
            #pragma unroll
            for (int j = 0; j < 4; ++j) {
                kreg[j] = *(const u16x8*)(kstage + k0n * HDIM + j * 8);
                vreg[j] = *(const u16x8*)(vstage + k0n + j * 8);
            }
        }
        __syncthreads();

        int k0 = kt * 32;
        fx4 s0 = (fx4){0.f,0.f,0.f,0.f}, s1 = (fx4){0.f,0.f,0.f,0.f};
        #pragma unroll
        for (int c = 0; c < 8; ++c) {
            u16x8 ka = *(const u16x8*)&Ks[lane16 * 264 + c * 32 + quad * 8];
            u16x8 kb = *(const u16x8*)&Ks[(16 + lane16) * 264 + c * 32 + quad * 8];
            s0 = mfma16(ka, qf[c], s0);
            s1 = mfma16(kb, qf[c], s1);
        }

        float p0[4], p1[4];
        int q = q0w + lane16;
        #pragma unroll
        for (int r = 0; r < 4; ++r) {
            int ka_ = k0 + quad * 4 + r;
            float e0 = exp2f(s0[r] * Cs2);
            float e1 = exp2f(s1[r] * Cs2);
            p0[r] = (ka_      <= q) ? e0 : 0.f;
            p1[r] = (ka_ + 16 <= q) ? e1 : 0.f;
            lsum += p0[r] + p1[r];
        }

        u16x8 pf;
        #pragma unroll
        for (int j = 0; j < 8; ++j) {
            int srcLane = ((((quad << 1) + (j >> 2)) & 3) << 4) | lane16;
            float v0 = __shfl(p0[j & 3], srcLane, 64);
            float v1 = __shfl(p1[j & 3], srcLane, 64);
            pf[j] = f2bf(quad >= 2 ? v1 : v0);
        }

        #pragma unroll
        for (int ft = 0; ft < 16; ++ft) {
            u16x8 vf = *(const u16x8*)&Vs[(ft * 16 + lane16) * 40 + quad * 8];
            o[ft] = mfma16(pf, vf, o[ft]);
        }
    }

    lsum += __shfl_xor(lsum, 16, 64);
    lsum += __shfl_xor(lsum, 32, 64);

    if (kc == 3) {
        float linv = 1.f / lsum;
        float inv[4];
        #pragma unroll
        for (int r = 0; r < 4; ++r) inv[r] = __shfl(linv, quad * 4 + r, 64);
        int b = bh / 3, h = bh - (bh / 3) * 3;
        unsigned short* hp = heads + (b * SEQ + q0w + quad * 4) * EMBD + h * HDIM + lane16;
        #pragma unroll
        for (int ft = 0; ft < 16; ++ft)
            #pragma unroll
            for (int r = 0; r < 4; ++r)
                hp[r * EMBD + ft * 16] = f2bf(o[ft][r] * inv[r]);
    } else {
        int slot = (bh * 16 + (qt - 16)) * 2 + kc;
        float* Op = Opart + slot * 16384 + (w * 16 + quad * 4) * 256 + lane16;
        #pragma unroll
        for (int ft = 0; ft < 16; ++ft)
            #pragma unroll
            for (int r = 0; r < 4; ++r)
                Op[r * 256 + ft * 16] = o[ft][r];
        if (quad == 0) Lpart[slot * 64 + w * 16 + lane16] = lsum;
    }
}

// ---------------------------------------------------------------------------
// Kernel 4: combine split-k partials (qt>=16), normalize, write heads bf16.
// (exact R5 version)
// ---------------------------------------------------------------------------
__global__ __launch_bounds__(256) void combine_kernel(
    const float* __restrict__ Opart, const float* __restrict__ Lpart,
    unsigned short* __restrict__ heads)
{
    int t = blockIdx.x;              // bh*16 + (qt-16)
    int bh = t >> 4, qt = (t & 15) + 16;
    int s0 = t * 2, s1 = s0 + 1;
    int tid = threadIdx.x;
    int row = tid >> 2, fseg = (tid & 3) * 64;
    float l = Lpart[s0 * 64 + row] + Lpart[s1 * 64 + row];
    float inv = 1.f / l;
    const fx4* O0 = (const fx4*)(Opart + s0 * 16384 + row * 256 + fseg);
    const fx4* O1 = (const fx4*)(Opart + s1 * 16384 + row * 256 + fseg);
    int b = bh / 3, h = bh - (bh / 3) * 3;
    unsigned short* hp = heads + (b * SEQ + qt * 64 + row) * EMBD + h * HDIM + fseg;
    #pragma unroll
    for (int i = 0; i < 16; ++i) {
        fx4 v = O0[i] + O1[i];
        u16x4 pk;
        pk[0] = f2bf(v[0] * inv); pk[1] = f2bf(v[1] * inv);
        pk[2] = f2bf(v[2] * inv); pk[3] = f2bf(v[3] * inv);
        *(u16x4*)(hp + i * 4) = pk;
    }
}

// ---------------------------------------------------------------------------
// Kernel 5: output projection — BK=64 + XOR chunk swizzle (exact R5 winner).
// ---------------------------------------------------------------------------
__global__ __launch_bounds__(256) void outproj_kernel(
    const unsigned short* __restrict__ A, const unsigned short* __restrict__ Wot,
    const float* __restrict__ bo, float* __restrict__ out)
{
    __shared__ alignas(16) unsigned short S[16384];
    unsigned short* As = S;
    unsigned short* Bs = S + 8192;

    int m0 = blockIdx.x * 128, n0 = blockIdx.y * 128;
    int tid = threadIdx.x;
    int w = tid >> 6, ln = tid & 63;
    int lane16 = ln & 15, quad = ln >> 4;
    int mw = (w & 1) * 64, nw = (w >> 1) * 64;

    fx4 acc[4][4];
    #pragma unroll
    for (int i = 0; i < 4; ++i)
        #pragma unroll
        for (int j = 0; j < 4; ++j) acc[i][j] = (fx4){0.f, 0.f, 0.f, 0.f};

    const unsigned short *Ag[4], *Wg[4];
    #pragma unroll
    for (int i = 0; i < 4; ++i) {
        int c = tid + 256 * i;
        int R = c >> 3;
        int So = (((c & 7) ^ (R & 7)) * 8);
        Ag[i] = A + (m0 + R) * EMBD + So;
        Wg[i] = Wot + (n0 + R) * EMBD + So;
    }
    int ca0 = ((quad + 0) ^ (lane16 & 7)) * 8;
    int ca1 = ((quad + 4) ^ (lane16 & 7)) * 8;

    for (int kb = 0; kb < EMBD; kb += 64) {
        __syncthreads();
        #pragma unroll
        for (int i = 0; i < 4; ++i) {
            gl_lds16(Ag[i] + kb, &As[(tid + 256 * i) * 8]);
            gl_lds16(Wg[i] + kb, &Bs[(tid + 256 * i) * 8]);
        }
        __syncthreads();

        #pragma unroll
        for (int kh = 0; kh < 2; ++kh) {
            int co = kh ? ca1 : ca0;
            u16x8 af[4], bf[4];
            #pragma unroll
            for (int i = 0; i < 4; ++i) {
                af[i] = *(const u16x8*)&As[(mw + i * 16 + lane16) * 64 + co];
                bf[i] = *(const u16x8*)&Bs[(nw + i * 16 + lane16) * 64 + co];
            }
            #pragma unroll
            for (int i = 0; i < 4; ++i)
                #pragma unroll
                for (int j = 0; j < 4; ++j)
                    acc[i][j] = mfma16(af[i], bf[j], acc[i][j]);
        }
    }

    #pragma unroll
    for (int i = 0; i < 4; ++i) {
        int mb = m0 + mw + i * 16 + quad * 4;
        #pragma unroll
        for (int j = 0; j < 4; ++j) {
            int n = n0 + nw + j * 16 + lane16;
            float bias = bo[n];
            #pragma unroll
            for (int r = 0; r < 4; ++r)
                out[(mb + r) * EMBD + n] = acc[i][j][r] + bias;
        }
    }
}

// ---------------------------------------------------------------------------
extern "C" void kernel_launch(void* const* d_in, const int* in_sizes, int n_in,
                              void* d_out, int out_size, void* d_ws, size_t ws_size,
                              hipStream_t stream) {
    const float* Ak = (const float*)d_in[0];
    const float* Av = (const float*)d_in[1];
    const float* Aq = (const float*)d_in[2];
    const float* Wk = (const float*)d_in[3];
    const float* Wv = (const float*)d_in[4];
    const float* Wq = (const float*)d_in[5];
    const float* Wo = (const float*)d_in[6];
    const float* bo = (const float*)d_in[7];
    float* out = (float*)d_out;

    char* base = (char*)d_ws;
    unsigned short* Wt    = (unsigned short*)(base);               // 3.54 MB
    unsigned short* Wot   = (unsigned short*)(base + 3538944);     // 1.18 MB
    unsigned short* Abf   = (unsigned short*)(base + 4718592);     // 37.75 MB
    unsigned short* Kg    = (unsigned short*)(base + 42467328);    // 12.58 MB
    unsigned short* Vg    = (unsigned short*)(base + 55050240);    // 12.58 MB
    unsigned short* Qg    = (unsigned short*)(base + 67633152);    // 12.58 MB
    unsigned short* heads = (unsigned short*)(base + 80216064);    // 12.58 MB
    // split-k partials overlay the Abf region (Abf dead after proj_kernel)
    float* Opart = (float*)(base + 4718592);                       // 25.17 MB
    float* Lpart = (float*)(base + 4718592 + 25165824);            // 98 KB

    castAw_kernel<<<dim3(9792), dim3(256), 0, stream>>>(
        Ak, Av, Aq, Wk, Wv, Wq, Wo, Abf, Wt, Wot);
    proj_kernel<<<dim3(64, 6, 3), dim3(256), 0, stream>>>(
        Abf, Wt, Kg, Vg, Qg);
    attn_kernel<<<dim3(288), dim3(256), 0, stream>>>(
        Kg, Vg, Qg, heads, Opart, Lpart, 0);
    attn_kernel<<<dim3(288), dim3(256), 0, stream>>>(
        Kg, Vg, Qg, heads, Opart, Lpart, 1);
    combine_kernel<<<dim3(192), dim3(256), 0, stream>>>(Opart, Lpart, heads);
    outproj_kernel<<<dim3(64, 6), dim3(256), 0, stream>>>(heads, Wot, bo, out);
}

// Round 14
// 276.583 us; speedup vs baseline: 1.2130x; 1.2130x over previous
//
#include <hip/hip_runtime.h>

#define BATCH 4
#define NHEADS 3
#define SEQ 2048
#define HDIM 256
#define EMBD 768
#define MTOT (BATCH*SEQ)          // 8192
#define WSZ (NHEADS*EMBD*HDIM)    // 589824 per projection weight

typedef unsigned short u16x8 __attribute__((ext_vector_type(8)));
typedef unsigned short u16x4 __attribute__((ext_vector_type(4)));
typedef __bf16 bf16x8 __attribute__((ext_vector_type(8)));
typedef float fx4 __attribute__((ext_vector_type(4)));

__device__ __forceinline__ unsigned short f2bf(float x) {
    union { float f; unsigned int u; } v; v.f = x;
    unsigned int r = v.u + 0x7fffu + ((v.u >> 16) & 1u);
    return (unsigned short)(r >> 16);
}

__device__ __forceinline__ fx4 mfma16(u16x8 a, u16x8 b, fx4 c) {
    return __builtin_amdgcn_mfma_f32_16x16x32_bf16(
        __builtin_bit_cast(bf16x8, a), __builtin_bit_cast(bf16x8, b), c, 0, 0, 0);
}

// async global->LDS, 16B per lane. LDS dest must be wave-uniform-base +
// lane*16 contiguous (m97/m104 constraint) — callers pass &lds[t*8shorts].
__device__ __forceinline__ void gl_lds16(const unsigned short* g, unsigned short* l) {
    __builtin_amdgcn_global_load_lds(
        (const __attribute__((address_space(1))) unsigned int*)g,
        (__attribute__((address_space(3))) unsigned int*)l, 16, 0, 0);
}

// attn work schedule per (b,h): entries qt*4+kc, kc in {0,1}=k-chunk (qt>=16,
// writes partials), kc=3 = whole causal range (qt<16, writes heads directly).
// (exact R5 schedule — 48 entries x 12 bh = 576 blocks, single launch again)
__device__ const unsigned char attn_sched[48] = {
    124,125, 63, 120,121, 116,117, 59, 112,113, 108,109, 55, 104,105,
    100,101, 51,  96, 97,  92, 93, 47,  88, 89,  84, 85, 43,  80, 81,
     76, 77, 39,  72, 73,  68, 69, 35,  64, 65,  31, 27, 23, 19, 15,
     11,  7,  3
};

// ---------------------------------------------------------------------------
// Kernel 1: cast A inputs fp32->bf16 + weight cast/transpose. (unchanged)
// ---------------------------------------------------------------------------
__global__ __launch_bounds__(256) void castAw_kernel(
    const float* __restrict__ Ak, const float* __restrict__ Av,
    const float* __restrict__ Aq,
    const float* __restrict__ Wk, const float* __restrict__ Wv,
    const float* __restrict__ Wq, const float* __restrict__ Wo,
    unsigned short* __restrict__ Abf, unsigned short* __restrict__ Wt,
    unsigned short* __restrict__ Wot)
{
    __shared__ float tile[64][65];
    int bx = blockIdx.x;
    if (bx < 9216) {            // A cast: 3 * 8192*768 elems, 8 per thread
        int e = (bx * 256 + threadIdx.x) * 8;
        int t = e / (MTOT * EMBD);
        int r = e - t * (MTOT * EMBD);
        const float* A = (t == 0) ? Ak : (t == 1) ? Av : Aq;
        const fx4* s = (const fx4*)(A + r);
        fx4 v0 = s[0], v1 = s[1];
        u16x8 o;
        o[0]=f2bf(v0[0]); o[1]=f2bf(v0[1]); o[2]=f2bf(v0[2]); o[3]=f2bf(v0[3]);
        o[4]=f2bf(v1[0]); o[5]=f2bf(v1[1]); o[6]=f2bf(v1[2]); o[7]=f2bf(v1[3]);
        *(u16x8*)(Abf + e) = o;
        return;
    }
    int z = bx - 9216;          // weight transpose via 64x64 LDS tile
    const float* src; unsigned short* dst;
    int src_ld, dst_ld, e0, f0;
    if (z < 432) {
        int t = z / 144, rem = z - t * 144;
        int h = rem / 48, tl = rem - h * 48;
        e0 = (tl % 12) * 64; f0 = (tl / 12) * 64;
        const float* W = (t == 0) ? Wk : (t == 1) ? Wv : Wq;
        src = W + h * 768 * 256; src_ld = 256;
        dst = Wt + t * WSZ + h * 256 * 768; dst_ld = 768;
    } else {
        int zz = z - 432;
        e0 = (zz % 12) * 64; f0 = (zz / 12) * 64;
        src = Wo; src_ld = 768;
        dst = Wot; dst_ld = 768;
    }
    int tx = threadIdx.x & 63, ty4 = threadIdx.x >> 6;
    #pragma unroll
    for (int i = 0; i < 16; ++i) {
        int r = ty4 + i * 4;
        tile[r][tx] = src[(e0 + r) * src_ld + f0 + tx];
    }
    __syncthreads();
    #pragma unroll
    for (int i = 0; i < 16; ++i) {
        int r = ty4 + i * 4;
        dst[(f0 + r) * dst_ld + e0 + tx] = f2bf(tile[tx][r]);
    }
}

// ---------------------------------------------------------------------------
// Kernel 2: projection GEMM, BK=64 + XOR chunk swizzle (exact R5 winner).
// ---------------------------------------------------------------------------
__global__ __launch_bounds__(256) void proj_kernel(
    const unsigned short* __restrict__ Abf, const unsigned short* __restrict__ Wt,
    unsigned short* __restrict__ Kg, unsigned short* __restrict__ Vg,
    unsigned short* __restrict__ Qg)
{
    __shared__ alignas(16) unsigned short S[17408];
    unsigned short* As = S;
    unsigned short* Bs = S + 8192;

    int z = blockIdx.z;
    const unsigned short* A = Abf + z * (MTOT * EMBD);
    int m0 = blockIdx.x * 128;
    int h = blockIdx.y >> 1, fbase = (blockIdx.y & 1) * 128;
    const unsigned short* W = Wt + z * WSZ + (h * 256 + fbase) * EMBD;

    int tid = threadIdx.x;
    int w = tid >> 6, ln = tid & 63;
    int lane16 = ln & 15, quad = ln >> 4;
    int mw = (w & 1) * 64, nw = (w >> 1) * 64;

    fx4 acc[4][4];
    #pragma unroll
    for (int i = 0; i < 4; ++i)
        #pragma unroll
        for (int j = 0; j < 4; ++j) acc[i][j] = (fx4){0.f, 0.f, 0.f, 0.f};

    const unsigned short *Ag[4], *Wg[4];
    #pragma unroll
    for (int i = 0; i < 4; ++i) {
        int c = tid + 256 * i;
        int R = c >> 3;
        int So = (((c & 7) ^ (R & 7)) * 8);
        Ag[i] = A + (m0 + R) * EMBD + So;
        Wg[i] = W + R * EMBD + So;
    }

    int ca0 = ((quad + 0) ^ (lane16 & 7)) * 8;
    int ca1 = ((quad + 4) ^ (lane16 & 7)) * 8;

    for (int kb = 0; kb < EMBD; kb += 64) {
        __syncthreads();
        #pragma unroll
        for (int i = 0; i < 4; ++i) {
            gl_lds16(Ag[i] + kb, &As[(tid + 256 * i) * 8]);
            gl_lds16(Wg[i] + kb, &Bs[(tid + 256 * i) * 8]);
        }
        __syncthreads();

        #pragma unroll
        for (int kh = 0; kh < 2; ++kh) {
            int co = kh ? ca1 : ca0;
            u16x8 af[4], bf[4];
            #pragma unroll
            for (int i = 0; i < 4; ++i) {
                af[i] = *(const u16x8*)&As[(mw + i * 16 + lane16) * 64 + co];
                bf[i] = *(const u16x8*)&Bs[(nw + i * 16 + lane16) * 64 + co];
            }
            #pragma unroll
            for (int i = 0; i < 4; ++i)
                #pragma unroll
                for (int j = 0; j < 4; ++j)
                    acc[i][j] = mfma16(af[i], bf[j], acc[i][j]);
        }
    }

    __syncthreads();
    int b = m0 >> 11, sq0 = m0 & 2047;

    if (z == 1) {
        #pragma unroll
        for (int i = 0; i < 4; ++i)
            #pragma unroll
            for (int j = 0; j < 4; ++j) {
                int fl = nw + j * 16 + lane16;
                int ml = mw + i * 16 + quad * 4;
                u16x4 pk;
                pk[0] = f2bf(acc[i][j][0]); pk[1] = f2bf(acc[i][j][1]);
                pk[2] = f2bf(acc[i][j][2]); pk[3] = f2bf(acc[i][j][3]);
                *(u16x4*)&S[fl * 136 + ml] = pk;
            }
        __syncthreads();
        int fl = tid >> 1, mseg = (tid & 1) * 64;
        const unsigned short* srcp = &S[fl * 136 + mseg];
        unsigned short* dstp = Vg + ((b * NHEADS + h) * HDIM + fbase + fl) * SEQ + sq0 + mseg;
        #pragma unroll
        for (int c = 0; c < 8; ++c)
            *(u16x8*)(dstp + c * 8) = *(const u16x8*)(srcp + c * 8);
    } else {
        #pragma unroll
        for (int i = 0; i < 4; ++i)
            #pragma unroll
            for (int j = 0; j < 4; ++j) {
                int fl = nw + j * 16 + lane16;
                int ml = mw + i * 16 + quad * 4;
                #pragma unroll
                for (int r = 0; r < 4; ++r)
                    S[(ml + r) * 136 + fl] = f2bf(acc[i][j][r]);
            }
        __syncthreads();
        unsigned short* dst0 = (z == 0) ? Kg : Qg;
        int ml = tid >> 1, fseg = (tid & 1) * 64;
        const unsigned short* srcp = &S[ml * 136 + fseg];
        unsigned short* dstp = dst0 + ((b * NHEADS + h) * SEQ + sq0 + ml) * HDIM + fbase + fseg;
        #pragma unroll
        for (int c = 0; c < 8; ++c)
            *(u16x8*)(dstp + c * 8) = *(const u16x8*)(srcp + c * 8);
    }
}

// ---------------------------------------------------------------------------
// Kernel 3: causal attention — R5 body, CHANGED: LDS K/V double-buffer with
// ONE barrier per tile (was 2). Per tile: compute(cur) overlaps
// ds_write(next -> buf^1) + global prefetch issue; barrier at end publishes
// buf^1 and guards buf[cur] reuse. Data paths/layouts/schedule identical to
// the measured 80us kernel. R11 measured the per-tile chain as latency-
// exposed (half-grid -> 0.84x time at 0.5x work); this removes the barrier +
// ds_write serialization from that chain. LDS 37.4 -> 73KB (2 blocks/CU,
// ~= current 2.25 avg).
// ---------------------------------------------------------------------------
__global__ __launch_bounds__(256) void attn_kernel(
    const unsigned short* __restrict__ Kg, const unsigned short* __restrict__ Vg,
    const unsigned short* __restrict__ Qg, unsigned short* __restrict__ heads,
    float* __restrict__ Opart, float* __restrict__ Lpart)
{
    __shared__ alignas(16) unsigned short Ks[2 * 32 * 264];   // 33.8 KB
    __shared__ alignas(16) unsigned short Vs[2 * 256 * 40];   // 41.0 KB

    int bx = blockIdx.x;
    int bh = bx % 12;
    int ent = attn_sched[bx / 12];
    int qt = ent >> 2, kc = ent & 3;
    int tid = threadIdx.x;
    int w = tid >> 6, ln = tid & 63;
    int lane16 = ln & 15, quad = ln >> 4;
    int q0w = qt * 64 + w * 16;

    const unsigned short* Kbase = Kg + bh * (SEQ * HDIM);
    const unsigned short* Vbase = Vg + bh * (SEQ * HDIM);  // [f][s]
    const unsigned short* Qbase = Qg + bh * (SEQ * HDIM);

    u16x8 qf[8];
    {
        const unsigned short* qrow = Qbase + (q0w + lane16) * HDIM + quad * 8;
        #pragma unroll
        for (int c = 0; c < 8; ++c) qf[c] = *(const u16x8*)(qrow + c * 32);
    }

    fx4 o[16];
    #pragma unroll
    for (int i = 0; i < 16; ++i) o[i] = (fx4){0.f, 0.f, 0.f, 0.f};
    float lsum = 0.f;

    const float Cs2 = 0.03188010519640429f;  // log2(e)/sqrt(2048)

    int t0, t1;
    if (kc == 3) { t0 = 0; t1 = 2 * qt + 2; }
    else         { t0 = kc * (qt + 1); t1 = t0 + qt + 1; }

    int ksrow = tid >> 3, kseg = tid & 7;
    const unsigned short* kstage = Kbase + ksrow * HDIM + kseg * 32;
    const unsigned short* vstage = Vbase + tid * SEQ;
    unsigned short* kd0 = &Ks[ksrow * 264 + kseg * 32];
    unsigned short* vd0 = &Vs[tid * 40];

    u16x8 kreg[4], vreg[4];
    {   // load tile t0
        int k0 = t0 * 32;
        #pragma unroll
        for (int j = 0; j < 4; ++j) {
            kreg[j] = *(const u16x8*)(kstage + k0 * HDIM + j * 8);
            vreg[j] = *(const u16x8*)(vstage + k0 + j * 8);
        }
    }
    {   // publish buf0
        u16x8* kd = (u16x8*)kd0;
        kd[0] = kreg[0]; kd[1] = kreg[1]; kd[2] = kreg[2]; kd[3] = kreg[3];
        u16x8* vd = (u16x8*)vd0;
        vd[0] = vreg[0]; vd[1] = vreg[1]; vd[2] = vreg[2]; vd[3] = vreg[3];
    }
    if (t0 + 1 < t1) {  // prefetch tile t0+1 into regs
        int k0n = (t0 + 1) * 32;
        #pragma unroll
        for (int j = 0; j < 4; ++j) {
            kreg[j] = *(const u16x8*)(kstage + k0n * HDIM + j * 8);
            vreg[j] = *(const u16x8*)(vstage + k0n + j * 8);
        }
    }
    __syncthreads();

    for (int kt = t0; kt < t1; ++kt) {
        int cur = (kt - t0) & 1;
        const unsigned short* KsC = &Ks[cur * (32 * 264)];
        const unsigned short* VsC = &Vs[cur * (256 * 40)];

        int k0 = kt * 32;
        fx4 s0 = (fx4){0.f,0.f,0.f,0.f}, s1 = (fx4){0.f,0.f,0.f,0.f};
        #pragma unroll
        for (int c = 0; c < 8; ++c) {
            u16x8 ka = *(const u16x8*)&KsC[lane16 * 264 + c * 32 + quad * 8];
            u16x8 kb = *(const u16x8*)&KsC[(16 + lane16) * 264 + c * 32 + quad * 8];
            s0 = mfma16(ka, qf[c], s0);
            s1 = mfma16(kb, qf[c], s1);
        }

        float p0[4], p1[4];
        int q = q0w + lane16;
        #pragma unroll
        for (int r = 0; r < 4; ++r) {
            int ka_ = k0 + quad * 4 + r;
            float e0 = exp2f(s0[r] * Cs2);
            float e1 = exp2f(s1[r] * Cs2);
            p0[r] = (ka_      <= q) ? e0 : 0.f;
            p1[r] = (ka_ + 16 <= q) ? e1 : 0.f;
            lsum += p0[r] + p1[r];
        }

        u16x8 pf;
        #pragma unroll
        for (int j = 0; j < 8; ++j) {
            int srcLane = ((((quad << 1) + (j >> 2)) & 3) << 4) | lane16;
            float v0 = __shfl(p0[j & 3], srcLane, 64);
            float v1 = __shfl(p1[j & 3], srcLane, 64);
            pf[j] = f2bf(quad >= 2 ? v1 : v0);
        }

        // stage tile kt+1 into buf^1 (overlaps with PV below; different
        // buffer, no intra-iteration hazard), then prefetch tile kt+2.
        if (kt + 1 < t1) {
            u16x8* kd = (u16x8*)(kd0 + (cur ^ 1) * (32 * 264));
            kd[0] = kreg[0]; kd[1] = kreg[1]; kd[2] = kreg[2]; kd[3] = kreg[3];
            u16x8* vd = (u16x8*)(vd0 + (cur ^ 1) * (256 * 40));
            vd[0] = vreg[0]; vd[1] = vreg[1]; vd[2] = vreg[2]; vd[3] = vreg[3];
            if (kt + 2 < t1) {
                int k0n = (kt + 2) * 32;
                #pragma unroll
                for (int j = 0; j < 4; ++j) {
                    kreg[j] = *(const u16x8*)(kstage + k0n * HDIM + j * 8);
                    vreg[j] = *(const u16x8*)(vstage + k0n + j * 8);
                }
            }
        }

        #pragma unroll
        for (int ft = 0; ft < 16; ++ft) {
            u16x8 vf = *(const u16x8*)&VsC[(ft * 16 + lane16) * 40 + quad * 8];
            o[ft] = mfma16(pf, vf, o[ft]);
        }

        __syncthreads();   // publish buf^1; all reads of buf[cur] complete
    }

    lsum += __shfl_xor(lsum, 16, 64);
    lsum += __shfl_xor(lsum, 32, 64);

    if (kc == 3) {
        float linv = 1.f / lsum;
        float inv[4];
        #pragma unroll
        for (int r = 0; r < 4; ++r) inv[r] = __shfl(linv, quad * 4 + r, 64);
        int b = bh / 3, h = bh - (bh / 3) * 3;
        unsigned short* hp = heads + (b * SEQ + q0w + quad * 4) * EMBD + h * HDIM + lane16;
        #pragma unroll
        for (int ft = 0; ft < 16; ++ft)
            #pragma unroll
            for (int r = 0; r < 4; ++r)
                hp[r * EMBD + ft * 16] = f2bf(o[ft][r] * inv[r]);
    } else {
        int slot = (bh * 16 + (qt - 16)) * 2 + kc;
        float* Op = Opart + slot * 16384 + (w * 16 + quad * 4) * 256 + lane16;
        #pragma unroll
        for (int ft = 0; ft < 16; ++ft)
            #pragma unroll
            for (int r = 0; r < 4; ++r)
                Op[r * 256 + ft * 16] = o[ft][r];
        if (quad == 0) Lpart[slot * 64 + w * 16 + lane16] = lsum;
    }
}

// ---------------------------------------------------------------------------
// Kernel 4: combine split-k partials (qt>=16), normalize, write heads bf16.
// (exact R5 version)
// ---------------------------------------------------------------------------
__global__ __launch_bounds__(256) void combine_kernel(
    const float* __restrict__ Opart, const float* __restrict__ Lpart,
    unsigned short* __restrict__ heads)
{
    int t = blockIdx.x;              // bh*16 + (qt-16)
    int bh = t >> 4, qt = (t & 15) + 16;
    int s0 = t * 2, s1 = s0 + 1;
    int tid = threadIdx.x;
    int row = tid >> 2, fseg = (tid & 3) * 64;
    float l = Lpart[s0 * 64 + row] + Lpart[s1 * 64 + row];
    float inv = 1.f / l;
    const fx4* O0 = (const fx4*)(Opart + s0 * 16384 + row * 256 + fseg);
    const fx4* O1 = (const fx4*)(Opart + s1 * 16384 + row * 256 + fseg);
    int b = bh / 3, h = bh - (bh / 3) * 3;
    unsigned short* hp = heads + (b * SEQ + qt * 64 + row) * EMBD + h * HDIM + fseg;
    #pragma unroll
    for (int i = 0; i < 16; ++i) {
        fx4 v = O0[i] + O1[i];
        u16x4 pk;
        pk[0] = f2bf(v[0] * inv); pk[1] = f2bf(v[1] * inv);
        pk[2] = f2bf(v[2] * inv); pk[3] = f2bf(v[3] * inv);
        *(u16x4*)(hp + i * 4) = pk;
    }
}

// ---------------------------------------------------------------------------
// Kernel 5: output projection — BK=64 + XOR chunk swizzle (exact R5 winner).
// ---------------------------------------------------------------------------
__global__ __launch_bounds__(256) void outproj_kernel(
    const unsigned short* __restrict__ A, const unsigned short* __restrict__ Wot,
    const float* __restrict__ bo, float* __restrict__ out)
{
    __shared__ alignas(16) unsigned short S[16384];
    unsigned short* As = S;
    unsigned short* Bs = S + 8192;

    int m0 = blockIdx.x * 128, n0 = blockIdx.y * 128;
    int tid = threadIdx.x;
    int w = tid >> 6, ln = tid & 63;
    int lane16 = ln & 15, quad = ln >> 4;
    int mw = (w & 1) * 64, nw = (w >> 1) * 64;

    fx4 acc[4][4];
    #pragma unroll
    for (int i = 0; i < 4; ++i)
        #pragma unroll
        for (int j = 0; j < 4; ++j) acc[i][j] = (fx4){0.f, 0.f, 0.f, 0.f};

    const unsigned short *Ag[4], *Wg[4];
    #pragma unroll
    for (int i = 0; i < 4; ++i) {
        int c = tid + 256 * i;
        int R = c >> 3;
        int So = (((c & 7) ^ (R & 7)) * 8);
        Ag[i] = A + (m0 + R) * EMBD + So;
        Wg[i] = Wot + (n0 + R) * EMBD + So;
    }
    int ca0 = ((quad + 0) ^ (lane16 & 7)) * 8;
    int ca1 = ((quad + 4) ^ (lane16 & 7)) * 8;

    for (int kb = 0; kb < EMBD; kb += 64) {
        __syncthreads();
        #pragma unroll
        for (int i = 0; i < 4; ++i) {
            gl_lds16(Ag[i] + kb, &As[(tid + 256 * i) * 8]);
            gl_lds16(Wg[i] + kb, &Bs[(tid + 256 * i) * 8]);
        }
        __syncthreads();

        #pragma unroll
        for (int kh = 0; kh < 2; ++kh) {
            int co = kh ? ca1 : ca0;
            u16x8 af[4], bf[4];
            #pragma unroll
            for (int i = 0; i < 4; ++i) {
                af[i] = *(const u16x8*)&As[(mw + i * 16 + lane16) * 64 + co];
                bf[i] = *(const u16x8*)&Bs[(nw + i * 16 + lane16) * 64 + co];
            }
            #pragma unroll
            for (int i = 0; i < 4; ++i)
                #pragma unroll
                for (int j = 0; j < 4; ++j)
                    acc[i][j] = mfma16(af[i], bf[j], acc[i][j]);
        }
    }

    #pragma unroll
    for (int i = 0; i < 4; ++i) {
        int mb = m0 + mw + i * 16 + quad * 4;
        #pragma unroll
        for (int j = 0; j < 4; ++j) {
            int n = n0 + nw + j * 16 + lane16;
            float bias = bo[n];
            #pragma unroll
            for (int r = 0; r < 4; ++r)
                out[(mb + r) * EMBD + n] = acc[i][j][r] + bias;
        }
    }
}

// ---------------------------------------------------------------------------
extern "C" void kernel_launch(void* const* d_in, const int* in_sizes, int n_in,
                              void* d_out, int out_size, void* d_ws, size_t ws_size,
                              hipStream_t stream) {
    const float* Ak = (const float*)d_in[0];
    const float* Av = (const float*)d_in[1];
    const float* Aq = (const float*)d_in[2];
    const float* Wk = (const float*)d_in[3];
    const float* Wv = (const float*)d_in[4];
    const float* Wq = (const float*)d_in[5];
    const float* Wo = (const float*)d_in[6];
    const float* bo = (const float*)d_in[7];
    float* out = (float*)d_out;

    char* base = (char*)d_ws;
    unsigned short* Wt    = (unsigned short*)(base);               // 3.54 MB
    unsigned short* Wot   = (unsigned short*)(base + 3538944);     // 1.18 MB
    unsigned short* Abf   = (unsigned short*)(base + 4718592);     // 37.75 MB
    unsigned short* Kg    = (unsigned short*)(base + 42467328);    // 12.58 MB
    unsigned short* Vg    = (unsigned short*)(base + 55050240);    // 12.58 MB
    unsigned short* Qg    = (unsigned short*)(base + 67633152);    // 12.58 MB
    unsigned short* heads = (unsigned short*)(base + 80216064);    // 12.58 MB
    // split-k partials overlay the Abf region (Abf dead after proj_kernel)
    float* Opart = (float*)(base + 4718592);                       // 25.17 MB
    float* Lpart = (float*)(base + 4718592 + 25165824);            // 98 KB

    castAw_kernel<<<dim3(9792), dim3(256), 0, stream>>>(
        Ak, Av, Aq, Wk, Wv, Wq, Wo, Abf, Wt, Wot);
    proj_kernel<<<dim3(64, 6, 3), dim3(256), 0, stream>>>(
        Abf, Wt, Kg, Vg, Qg);
    attn_kernel<<<dim3(576), dim3(256), 0, stream>>>(
        Kg, Vg, Qg, heads, Opart, Lpart);
    combine_kernel<<<dim3(192), dim3(256), 0, stream>>>(Opart, Lpart, heads);
    outproj_kernel<<<dim3(64, 6), dim3(256), 0, stream>>>(heads, Wot, bo, out);
}